// Round 6
// baseline (322.715 us; speedup 1.0000x reference)
//
#include <hip/hip_runtime.h>
#include <stdint.h>

#define TPB 512

constexpr int Bb   = 8;    // batch
constexpr int Vv   = 200;  // vertices
constexpr int Tt   = 128;  // time
constexpr int CIN  = 128;  // concat channels
constexpr int COUT = 64;   // K_HEADS * D_HEAD

typedef __attribute__((ext_vector_type(8))) short bf16x8;
typedef __attribute__((ext_vector_type(4))) short short4v;
typedef __attribute__((ext_vector_type(4))) float f32x4;

// bf16 helpers (manual RNE) — verified R0-R4; do NOT replace with
// v_cvt_pk_bf16_f32 inline asm (R2 produced inf with it).
__device__ __forceinline__ unsigned short f2bf(float f) {
    union { float f; unsigned u; } x; x.f = f;
    unsigned r = x.u + 0x7fffu + ((x.u >> 16) & 1u);
    return (unsigned short)(r >> 16);
}
__device__ __forceinline__ unsigned pk2(float a, float b) {
    return (unsigned)f2bf(a) | ((unsigned)f2bf(b) << 16);
}

// 16x16x16 bf16 MFMA (K=16): used for QK^T (K=8 real) and PV.
#if __has_builtin(__builtin_amdgcn_mfma_f32_16x16x16bf16_1k)
#define MFMA16(a, b, c) __builtin_amdgcn_mfma_f32_16x16x16bf16_1k(a, b, c, 0, 0, 0)
#else
__device__ __forceinline__ f32x4 mfma16_asm(short4v a, short4v b, f32x4 c) {
    f32x4 d;
    asm("v_mfma_f32_16x16x16_bf16 %0, %1, %2, %3" : "=v"(d) : "v"(a), "v"(b), "v"(c));
    return d;
}
#define MFMA16(a, b, c) mfma16_asm(a, b, c)
#endif

// One block per (b, v). Fused per-round pipeline, LDS 40 KiB -> 4 blocks/CU:
//   kbuf bf16 K[128][64] @0        (8B-chunk swizzle ^(t&14))
//   vt   bf16 VT[64 dg][128 s] @16384 (col swizzle by dg quad-group)
//   xt   bf16 [16 t][128 c] @32768 (per-round staging)
//   qbuf bf16 [16 t][64 d]  @36864 (current round's Q tile only)
//   obuf bf16 [16 t][64 i]  @38912 (current round's attention output)
// Causality: attention tile tt=r needs only K/V tiles 0..r -> fuse
// proj/attn/outproj into one 8-round loop; Q and O live 1 tile each.
// Round r: seg1 {proj QKV tile r; outproj tile r-1} | barrier |
//          seg2 {attention tt=r; stage xt(r+1)}     | barrier |
__global__ __launch_bounds__(TPB, 8)
void tatt_fused(const float* __restrict__ x, const float* __restrict__ tem,
                const float* __restrict__ Wq, const float* __restrict__ bq,
                const float* __restrict__ Wk, const float* __restrict__ bk,
                const float* __restrict__ Wv, const float* __restrict__ bv,
                const float* __restrict__ Wo, const float* __restrict__ bo,
                float* __restrict__ out)
{
    __shared__ __align__(16) unsigned char smem[40960];
    unsigned short* kbuf = (unsigned short*)smem;            // K[128][64]
    unsigned short* vt   = (unsigned short*)(smem + 16384);  // VT[64][128]
    unsigned short* xt   = (unsigned short*)(smem + 32768);  // [16][128]
    unsigned short* qbuf = (unsigned short*)(smem + 36864);  // [16][64]
    unsigned short* obuf = (unsigned short*)(smem + 38912);  // [16][64]

    const int tid = threadIdx.x;
    const int w = tid >> 6, lane = tid & 63;
    const int l15 = lane & 15, qd = lane >> 4;
    const int b = blockIdx.x / Vv, v = blockIdx.x % Vv;
    const float QS = 1.44269504088896f * 0.35355339059327f;  // log2(e)/sqrt(8)

    const int ot_   = w & 3;               // this wave's proj/outproj tile
    const int obase = ot_ * 16 + qd * 4;
    const int qkoff = ((w * 2 + qd) ^ (l15 & 14)) << 2;  // head-w chunk offset
    const int vdg   = w * 8 + l15;                        // V^T row (d of head w)
    const int vswz  = ((vdg >> 2) & 3) << 4;

    // ---- W A-frag register cache (once per block, from float W) ----
    // waves 0-3: afr0 = Wq tile ot_, afr1 = Wk tile ot_
    // waves 4-7: afr0 = Wv tile ot_, afr1[0..1] = Wo tile ot_
    bf16x8 afr0[4], afr1[4];
    {
        const float* W0 = (w < 4) ? Wq : Wv;
        const float* base0 = W0 + (ot_ * 16 + l15) * CIN + qd * 8;
        #pragma unroll
        for (int kc = 0; kc < 4; ++kc) {
            float4 fa = *(const float4*)(base0 + kc * 32);
            float4 fb = *(const float4*)(base0 + kc * 32 + 4);
            union { bf16x8 v8; unsigned u[4]; } t;
            t.u[0] = pk2(fa.x, fa.y); t.u[1] = pk2(fa.z, fa.w);
            t.u[2] = pk2(fb.x, fb.y); t.u[3] = pk2(fb.z, fb.w);
            afr0[kc] = t.v8;
        }
        if (w < 4) {
            const float* base1 = Wk + (ot_ * 16 + l15) * CIN + qd * 8;
            #pragma unroll
            for (int kc = 0; kc < 4; ++kc) {
                float4 fa = *(const float4*)(base1 + kc * 32);
                float4 fb = *(const float4*)(base1 + kc * 32 + 4);
                union { bf16x8 v8; unsigned u[4]; } t;
                t.u[0] = pk2(fa.x, fa.y); t.u[1] = pk2(fa.z, fa.w);
                t.u[2] = pk2(fb.x, fb.y); t.u[3] = pk2(fb.z, fb.w);
                afr1[kc] = t.v8;
            }
        } else {
            const float* baseO = Wo + (ot_ * 16 + l15) * COUT + qd * 8;
            #pragma unroll
            for (int kc = 0; kc < 2; ++kc) {
                float4 fa = *(const float4*)(baseO + kc * 32);
                float4 fb = *(const float4*)(baseO + kc * 32 + 4);
                union { bf16x8 v8; unsigned u[4]; } t;
                t.u[0] = pk2(fa.x, fa.y); t.u[1] = pk2(fa.z, fa.w);
                t.u[2] = pk2(fb.x, fb.y); t.u[3] = pk2(fb.z, fb.w);
                afr1[kc] = t.v8;
            }
        }
    }

    // one 16x16 projection tile: C = A(W)*B(xt) + bias -> Q/K/V LDS
    auto projTile = [&](const bf16x8 (&A)[4], int p, const float* bp, int r) {
        f32x4 acc = {0.f, 0.f, 0.f, 0.f};
        const unsigned short* Bbp = xt + l15 * CIN;
        #pragma unroll
        for (int kc = 0; kc < 4; ++kc) {
            int phys = (kc * 4 + qd) ^ l15;
            bf16x8 bb = *(const bf16x8*)(Bbp + phys * 8);
            acc = __builtin_amdgcn_mfma_f32_16x16x32_bf16(A[kc], bb, acc, 0, 0, 0);
        }
        float4 bias = *(const float4*)(bp + obase);
        float bb4[4] = {bias.x, bias.y, bias.z, bias.w};
        if (p == 2) {
            // V^T[dg][t], column-swizzled by dg quad-group
            int tg = r * 16 + l15;
            #pragma unroll
            for (int rr = 0; rr < 4; ++rr) {
                int dg = obase + rr;
                int tp = tg ^ ((((dg >> 2) & 3)) << 4);
                vt[dg * 128 + tp] = f2bf(acc[rr] + bb4[rr]);
            }
        } else if (p == 1) {
            int tg = r * 16 + l15;
            ushort4 s4;
            s4.x = f2bf(acc[0] + bb4[0]); s4.y = f2bf(acc[1] + bb4[1]);
            s4.z = f2bf(acc[2] + bb4[2]); s4.w = f2bf(acc[3] + bb4[3]);
            int phys = (obase >> 2) ^ (tg & 14);
            *(ushort4*)(kbuf + tg * 64 + phys * 4) = s4;
        } else {
            // Q tile (local 16 rows), pre-scaled by log2(e)/sqrt(d)
            ushort4 s4;
            s4.x = f2bf((acc[0] + bb4[0]) * QS); s4.y = f2bf((acc[1] + bb4[1]) * QS);
            s4.z = f2bf((acc[2] + bb4[2]) * QS); s4.w = f2bf((acc[3] + bb4[3]) * QS);
            int phys = (obase >> 2) ^ (l15 & 14);
            *(ushort4*)(qbuf + l15 * 64 + phys * 4) = s4;
        }
    };

    // out-projection of obuf (one t-tile) + bias + relu, waves 4-7, tile ot_
    auto oproj = [&](int tile) {
        f32x4 acc = {0.f, 0.f, 0.f, 0.f};
        #pragma unroll
        for (int kc = 0; kc < 2; ++kc) {
            bf16x8 bb = *(const bf16x8*)(obuf + l15 * 64
                             + (((kc * 8 + qd * 2) ^ (l15 & 14)) << 2));
            acc = __builtin_amdgcn_mfma_f32_16x16x32_bf16(afr1[kc], bb, acc, 0, 0, 0);
        }
        float4 bias = *(const float4*)(bo + obase);
        int t = tile * 16 + l15;
        float vr[4] = {acc[0] + bias.x, acc[1] + bias.y,
                       acc[2] + bias.z, acc[3] + bias.w};
        #pragma unroll
        for (int rr = 0; rr < 4; ++rr) {
            float val = vr[rr];
            out[((b * COUT + obase + rr) * Vv + v) * Tt + t] = val > 0.f ? val : 0.f;
        }
    };

    // ---- staging map: thread owns (1 channel, 4 consecutive t) ----
    const int sc_ = tid >> 2, stq = tid & 3;
    const float* sbase = (sc_ < 64 ? x : tem)
        + ((b * 64 + (sc_ & 63)) * Vv + v) * Tt + stq * 4;
    const int clow = sc_ & 7, chi = sc_ >> 3;

    float4 pf = *(const float4*)sbase;  // tile 0
    {   // S(0)
        int t0 = stq * 4;
        xt[(t0 + 0) * CIN + ((chi ^ (t0 + 0)) << 3) + clow] = f2bf(pf.x);
        xt[(t0 + 1) * CIN + ((chi ^ (t0 + 1)) << 3) + clow] = f2bf(pf.y);
        xt[(t0 + 2) * CIN + ((chi ^ (t0 + 2)) << 3) + clow] = f2bf(pf.z);
        xt[(t0 + 3) * CIN + ((chi ^ (t0 + 3)) << 3) + clow] = f2bf(pf.w);
    }
    pf = *(const float4*)(sbase + 16);  // tile 1
    __syncthreads();  // xt(0) ready

    for (int r = 0; r < 8; ++r) {
        // ---------- seg1: projection tile r (+ outproj tile r-1) ----------
        if (w < 4) {
            projTile(afr0, 0, bq, r);   // Q
            projTile(afr1, 1, bk, r);   // K
        } else {
            projTile(afr0, 2, bv, r);   // V
            if (r > 0) oproj(r - 1);
        }
        __syncthreads();  // K/V tile r, Q tile ready; obuf consumed

        // ---------- seg2: stage xt(r+1); attention tt=r ----------
        if (r < 7) {
            int t0 = stq * 4;
            xt[(t0 + 0) * CIN + ((chi ^ (t0 + 0)) << 3) + clow] = f2bf(pf.x);
            xt[(t0 + 1) * CIN + ((chi ^ (t0 + 1)) << 3) + clow] = f2bf(pf.y);
            xt[(t0 + 2) * CIN + ((chi ^ (t0 + 2)) << 3) + clow] = f2bf(pf.z);
            xt[(t0 + 3) * CIN + ((chi ^ (t0 + 3)) << 3) + clow] = f2bf(pf.w);
        }
        if (r < 6) pf = *(const float4*)(sbase + (r + 2) * 16);  // prefetch

        short4v qf = {0, 0, 0, 0};
        if (qd < 2) qf = *(const short4v*)(qbuf + l15 * 64 + qkoff);
        f32x4 o0 = {0.f, 0.f, 0.f, 0.f}, o1 = {0.f, 0.f, 0.f, 0.f};
        float lac = 0.f;
        for (int st = 0; st <= r; ++st) {
            short4v kf = {0, 0, 0, 0};
            if (qd < 2) kf = *(const short4v*)(kbuf + (st * 16 + l15) * 64 + qkoff);
            short4v vf = {0, 0, 0, 0};
            if (l15 < 8) vf = *(const short4v*)(vt + vdg * 128 + ((st * 16 + qd * 4) ^ vswz));
            f32x4 z = {0.f, 0.f, 0.f, 0.f};
            f32x4 s = MFMA16(kf, qf, z);
            float p0 = __builtin_amdgcn_exp2f(s[0]);
            float p1 = __builtin_amdgcn_exp2f(s[1]);
            float p2 = __builtin_amdgcn_exp2f(s[2]);
            float p3 = __builtin_amdgcn_exp2f(s[3]);
            if (st == r) {  // diagonal tile: per-element causal mask (s<=t)
                p0 = (qd * 4 + 0) <= l15 ? p0 : 0.f;
                p1 = (qd * 4 + 1) <= l15 ? p1 : 0.f;
                p2 = (qd * 4 + 2) <= l15 ? p2 : 0.f;
                p3 = (qd * 4 + 3) <= l15 ? p3 : 0.f;
            }
            lac += (p0 + p1) + (p2 + p3);
            int pp0 = (int)pk2(p0, p1), pp1 = (int)pk2(p2, p3);
            short4v pfv;
            pfv[0] = (short)(pp0 & 0xffff); pfv[1] = (short)(pp0 >> 16);
            pfv[2] = (short)(pp1 & 0xffff); pfv[3] = (short)(pp1 >> 16);
            if (st & 1) o1 = MFMA16(vf, pfv, o1);
            else        o0 = MFMA16(vf, pfv, o0);
        }
        // row sum l(t): partials at (l15=t, qd); fold quads
        float l = lac;
        l += __shfl_xor(l, 16, 64);
        l += __shfl_xor(l, 32, 64);
        float rl = __builtin_amdgcn_rcpf(l);
        if (qd < 2) {  // O^T rows d=qd*4+reg, only d<8 real
            float r0 = (o0[0] + o1[0]) * rl, r1 = (o0[1] + o1[1]) * rl;
            float r2 = (o0[2] + o1[2]) * rl, r3 = (o0[3] + o1[3]) * rl;
            uint2 st2;
            st2.x = pk2(r0, r1);
            st2.y = pk2(r2, r3);
            *(uint2*)(obuf + l15 * 64 + qkoff) = st2;
        }
        __syncthreads();  // obuf(r) ready; xt(r+1) ready
    }

    // epilogue: out-projection of final tile
    if (w >= 4) oproj(7);
}

extern "C" void kernel_launch(void* const* d_in, const int* in_sizes, int n_in,
                              void* d_out, int out_size, void* d_ws, size_t ws_size,
                              hipStream_t stream) {
    (void)in_sizes; (void)n_in; (void)ws_size; (void)out_size; (void)d_ws;
    const float* x   = (const float*)d_in[0];
    const float* tem = (const float*)d_in[1];
    const float* Wq  = (const float*)d_in[2];
    const float* bq  = (const float*)d_in[3];
    const float* Wk  = (const float*)d_in[4];
    const float* bk  = (const float*)d_in[5];
    const float* Wv  = (const float*)d_in[6];
    const float* bv  = (const float*)d_in[7];
    const float* Wo  = (const float*)d_in[8];
    const float* bo  = (const float*)d_in[9];
    float* out = (float*)d_out;

    tatt_fused<<<dim3(Bb * Vv), dim3(TPB), 0, stream>>>(
        x, tem, Wq, bq, Wk, bk, Wv, bv, Wo, bo, out);
}

// Round 8
// 224.042 us; speedup vs baseline: 1.4404x; 1.4404x over previous
//
#include <hip/hip_runtime.h>
#include <stdint.h>

#define TPB 512

constexpr int Bb   = 8;    // batch
constexpr int Vv   = 200;  // vertices
constexpr int Tt   = 128;  // time
constexpr int CIN  = 128;  // concat channels
constexpr int COUT = 64;   // K_HEADS * D_HEAD

typedef __attribute__((ext_vector_type(8))) short bf16x8;
typedef __attribute__((ext_vector_type(4))) short short4v;
typedef __attribute__((ext_vector_type(4))) float f32x4;

// bf16 helpers (manual RNE) — verified R0-R4.
// BANNED: v_cvt_pk_bf16_f32 inline asm. Isolated A/B (R7) proved it
// produces inf on this toolchain (R2 failure root cause). Do not retry.
__device__ __forceinline__ unsigned short f2bf(float f) {
    union { float f; unsigned u; } x; x.f = f;
    unsigned r = x.u + 0x7fffu + ((x.u >> 16) & 1u);
    return (unsigned short)(r >> 16);
}
__device__ __forceinline__ unsigned pk2(float a, float b) {
    return (unsigned)f2bf(a) | ((unsigned)f2bf(b) << 16);
}

// 16x16x16 bf16 MFMA (K=16): used for QK^T (K=8 real) and PV.
#if __has_builtin(__builtin_amdgcn_mfma_f32_16x16x16bf16_1k)
#define MFMA16(a, b, c) __builtin_amdgcn_mfma_f32_16x16x16bf16_1k(a, b, c, 0, 0, 0)
#else
__device__ __forceinline__ f32x4 mfma16_asm(short4v a, short4v b, f32x4 c) {
    f32x4 d;
    asm("v_mfma_f32_16x16x16_bf16 %0, %1, %2, %3" : "=v"(d) : "v"(a), "v"(b), "v"(c));
    return d;
}
#define MFMA16(a, b, c) mfma16_asm(a, b, c)
#endif

// One block per (b, v). LDS 52 KiB -> 3 blocks/CU (R4-verified structure):
//   qk  bf16 Q[128][64] @0, K[128][64] @16384  (8B-chunk swizzle: phys_hc = hc ^ (t&14))
//   vt  bf16 VT[64 dg][128 s] @32768 (phase 1 + vfrag load)
//   ot  bf16 [128 t][64 i]    @32768 (overlays vt after vfrag barrier)
//   xt  bf16 [16 t][128 c]    @49152 (phase-1 staging, 8 rounds of 16 t)
// NOTE (R6 lesson): do NOT fuse phases into a long per-round pipeline —
// fragmenting out-stores into 64B chunks over the kernel lifetime blew
// HBM traffic 139->629 MB (RMW + L3 thrash), 114->216 us.
__global__ __launch_bounds__(TPB, 6)
void tatt_fused(const float* __restrict__ x, const float* __restrict__ tem,
                const float* __restrict__ Wq, const float* __restrict__ bq,
                const float* __restrict__ Wk, const float* __restrict__ bk,
                const float* __restrict__ Wv, const float* __restrict__ bv,
                const float* __restrict__ Wo, const float* __restrict__ bo,
                float* __restrict__ out)
{
    __shared__ __align__(16) unsigned char smem[53248];
    unsigned short* qk = (unsigned short*)smem;            // Q @0 (elts), K @8192 (elts)
    unsigned short* vt = (unsigned short*)(smem + 32768);  // VT [64][128]
    unsigned short* ot = (unsigned short*)(smem + 32768);  // overlays vt (after barrier)
    unsigned short* xt = (unsigned short*)(smem + 49152);  // [16][128]

    const int tid = threadIdx.x;
    const int w = tid >> 6, lane = tid & 63;
    const int l15 = lane & 15, qd = lane >> 4;
    const int b = blockIdx.x / Vv, v = blockIdx.x % Vv;
    const float QS = 1.44269504088896f * 0.35355339059327f;  // log2(e)/sqrt(8)

    // ---- A-fragment register cache (loaded once per block, from float W) ----
    // waves 0-3: Q tile (p=0, ot_=w) in afr0, K tile (p=1, ot_=w) in afr1
    // waves 4-7: V tile (p=2, ot_=w-4) in afr0
    bf16x8 afr0[4], afr1[4];
    {
        const float* W0 = (w < 4) ? Wq : Wv;
        const int o0_ = (w < 4) ? w : (w - 4);
        const float* base0 = W0 + (o0_ * 16 + l15) * CIN + qd * 8;
        #pragma unroll
        for (int kc = 0; kc < 4; ++kc) {
            float4 fa = *(const float4*)(base0 + kc * 32);
            float4 fb = *(const float4*)(base0 + kc * 32 + 4);
            union { bf16x8 v8; unsigned u[4]; } t;
            t.u[0] = pk2(fa.x, fa.y); t.u[1] = pk2(fa.z, fa.w);
            t.u[2] = pk2(fb.x, fb.y); t.u[3] = pk2(fb.z, fb.w);
            afr0[kc] = t.v8;
        }
        if (w < 4) {
            const float* base1 = Wk + (w * 16 + l15) * CIN + qd * 8;
            #pragma unroll
            for (int kc = 0; kc < 4; ++kc) {
                float4 fa = *(const float4*)(base1 + kc * 32);
                float4 fb = *(const float4*)(base1 + kc * 32 + 4);
                union { bf16x8 v8; unsigned u[4]; } t;
                t.u[0] = pk2(fa.x, fa.y); t.u[1] = pk2(fa.z, fa.w);
                t.u[2] = pk2(fb.x, fb.y); t.u[3] = pk2(fb.z, fb.w);
                afr1[kc] = t.v8;
            }
        }
    }

    // one 16x16 projection tile: C = A(W) * B(xt), bias, store to Q/K/V LDS
    auto tileC = [&](const bf16x8 (&A)[4], int p, int ot_, int r) {
        f32x4 acc = {0.f, 0.f, 0.f, 0.f};
        const unsigned short* Bbp = xt + l15 * CIN;
        #pragma unroll
        for (int kc = 0; kc < 4; ++kc) {
            int phys = (kc * 4 + qd) ^ l15;
            bf16x8 bb = *(const bf16x8*)(Bbp + phys * 8);
            acc = __builtin_amdgcn_mfma_f32_16x16x32_bf16(A[kc], bb, acc, 0, 0, 0);
        }
        const int obase = ot_ * 16 + qd * 4;
        const float* bp = (p == 0) ? bq : ((p == 1) ? bk : bv);
        float4 bias = *(const float4*)(bp + obase);
        float bb4[4] = {bias.x, bias.y, bias.z, bias.w};
        const int tg = r * 16 + l15;
        if (p == 2) {
            // V stored transposed: VT[dg][t], column-swizzled by dg quad-group
            #pragma unroll
            for (int rr = 0; rr < 4; ++rr) {
                int dg = obase + rr;
                int tp = tg ^ ((((dg >> 2) & 3)) << 4);
                vt[dg * 128 + tp] = f2bf(acc[rr] + bb4[rr]);
            }
        } else {
            // Q pre-scaled by log2(e)/sqrt(d); 8B-chunk swizzle ^(t&14)
            float sc = (p == 0) ? QS : 1.0f;
            ushort4 s4;
            s4.x = f2bf((acc[0] + bb4[0]) * sc);
            s4.y = f2bf((acc[1] + bb4[1]) * sc);
            s4.z = f2bf((acc[2] + bb4[2]) * sc);
            s4.w = f2bf((acc[3] + bb4[3]) * sc);
            int phys = (obase >> 2) ^ (tg & 14);
            *(ushort4*)(qk + p * 8192 + tg * 64 + phys * 4) = s4;
        }
    };

    // ---------------- phase 1: QKV projection, 8 rounds of 16 t ----------------
    {
        // staging: thread owns (1 channel, 4 consecutive t) -> one float4 load
        const int sc_ = tid >> 2;   // channel 0..127
        const int stq = tid & 3;    // t-quad
        const float* sbase = (sc_ < 64 ? x : tem)
            + ((b * 64 + (sc_ & 63)) * Vv + v) * Tt + stq * 4;
        float4 pf = *(const float4*)(sbase);
        const int clow = sc_ & 7, chi = sc_ >> 3;

        for (int r = 0; r < 8; ++r) {
            if (r) __syncthreads();           // prior round's B-frag reads done
            {
                int t0 = stq * 4;
                xt[(t0 + 0) * CIN + ((chi ^ (t0 + 0)) << 3) + clow] = f2bf(pf.x);
                xt[(t0 + 1) * CIN + ((chi ^ (t0 + 1)) << 3) + clow] = f2bf(pf.y);
                xt[(t0 + 2) * CIN + ((chi ^ (t0 + 2)) << 3) + clow] = f2bf(pf.z);
                xt[(t0 + 3) * CIN + ((chi ^ (t0 + 3)) << 3) + clow] = f2bf(pf.w);
            }
            if (r < 7) pf = *(const float4*)(sbase + (r + 1) * 16);  // T14 prefetch
            __syncthreads();                  // xt ready
            if (w < 4) { tileC(afr0, 0, w, r); tileC(afr1, 1, w, r); }
            else       { tileC(afr0, 2, w - 4, r); }
        }
    }
    __syncthreads();  // Q/K/VT complete

    // ---------------- phase 2: causal attention, wave = head ----------------
    // S^T = K*Q^T via 16x16x16 MFMA (K=8 real, qd<2 lanes carry data).
    // C-layout: col=l15=t, row=qd*4+reg=s. P^T (exp2, masked) feeds PV directly.
    {
        const int h = w;
        const int qkoff = ((h * 2 + qd) ^ (l15 & 14)) << 2;  // b64 chunk for qd<2
        // cache V A-frags: lane m=l15=d (valid <8), k=qd*4+j
        short4v vfrag[8];
        short4v qfrag[8];  // Q frags per tt (qk immutable through phase 2)
        {
            const int dg = h * 8 + l15;
            const int swz = ((dg >> 2) & 3) << 4;
            #pragma unroll
            for (int st = 0; st < 8; ++st) {
                short4v f = {0, 0, 0, 0};
                if (l15 < 8) {
                    int sp = (st * 16 + qd * 4) ^ swz;
                    f = *(const short4v*)(vt + dg * 128 + sp);
                }
                vfrag[st] = f;
            }
            #pragma unroll
            for (int st = 0; st < 8; ++st) {
                short4v qf = {0, 0, 0, 0};
                if (qd < 2) qf = *(const short4v*)(qk + (st * 16 + l15) * 64 + qkoff);
                qfrag[st] = qf;
            }
        }
        __syncthreads();  // all waves' vfrag done; vt region becomes ot

        bool dmask[4];
        #pragma unroll
        for (int r = 0; r < 4; ++r) dmask[r] = (qd * 4 + r) <= l15;  // diag: s<=t

        #pragma unroll
        for (int tt = 0; tt < 8; ++tt) {
            f32x4 o0 = {0.f, 0.f, 0.f, 0.f}, o1 = {0.f, 0.f, 0.f, 0.f};
            float lac = 0.f;
            #pragma unroll
            for (int st = 0; st < 8; ++st) {
                if (st <= tt) {  // compile-time pruned (full unroll)
                    short4v kf = {0, 0, 0, 0};
                    if (qd < 2) kf = *(const short4v*)(qk + 8192 + (st * 16 + l15) * 64 + qkoff);
                    f32x4 z = {0.f, 0.f, 0.f, 0.f};
                    f32x4 s = MFMA16(kf, qfrag[tt], z);
                    float p0 = __builtin_amdgcn_exp2f(s[0]);
                    float p1 = __builtin_amdgcn_exp2f(s[1]);
                    float p2 = __builtin_amdgcn_exp2f(s[2]);
                    float p3 = __builtin_amdgcn_exp2f(s[3]);
                    if (st == tt) {  // diagonal tile: per-element causal mask
                        p0 = dmask[0] ? p0 : 0.f;
                        p1 = dmask[1] ? p1 : 0.f;
                        p2 = dmask[2] ? p2 : 0.f;
                        p3 = dmask[3] ? p3 : 0.f;
                    }
                    lac += (p0 + p1) + (p2 + p3);
                    int pp0 = (int)pk2(p0, p1), pp1 = (int)pk2(p2, p3);
                    short4v pf;
                    pf[0] = (short)(pp0 & 0xffff); pf[1] = (short)(pp0 >> 16);
                    pf[2] = (short)(pp1 & 0xffff); pf[3] = (short)(pp1 >> 16);
                    if (st & 1) o1 = MFMA16(vfrag[st], pf, o1);
                    else        o0 = MFMA16(vfrag[st], pf, o0);
                }
            }
            // row sum l(t): partials live at (l15=t, qd); fold quads
            float l = lac;
            l += __shfl_xor(l, 16, 64);
            l += __shfl_xor(l, 32, 64);
            float rl = __builtin_amdgcn_rcpf(l);
            if (qd < 2) {  // O^T rows d=qd*4+reg, only d<8 real
                float r0 = (o0[0] + o1[0]) * rl, r1 = (o0[1] + o1[1]) * rl;
                float r2 = (o0[2] + o1[2]) * rl, r3 = (o0[3] + o1[3]) * rl;
                int t = tt * 16 + l15;
                uint2 st2;
                st2.x = pk2(r0, r1);
                st2.y = pk2(r2, r3);
                *(uint2*)(ot + t * 64 + (((h * 2 + qd) ^ (l15 & 14)) << 2)) = st2;
            }
        }
    }
    __syncthreads();

    // ---------------- phase 3: out-projection + bias + relu ----------------
    // wave w: t-tiles {2(w&3), 2(w&3)+1} x ot_ {2(w>>2), 2(w>>2)+1}.
    // Compute ALL 4 tiles first, then store grouped per output row so each
    // 128B line (32 consecutive t) is written by back-to-back instructions
    // from one wave (kills the partial-line HBM RMW seen in R4: WRITE 78MB).
    {
        const int tq3 = w & 3, ohB = (w >> 2) * 2;
        bf16x8 wof[2][2];
        #pragma unroll
        for (int oth = 0; oth < 2; ++oth) {
            const float* base = Wo + ((ohB + oth) * 16 + l15) * COUT + qd * 8;
            #pragma unroll
            for (int kc = 0; kc < 2; ++kc) {
                float4 fa = *(const float4*)(base + kc * 32);
                float4 fb = *(const float4*)(base + kc * 32 + 4);
                union { bf16x8 v8; unsigned u[4]; } t;
                t.u[0] = pk2(fa.x, fa.y); t.u[1] = pk2(fa.z, fa.w);
                t.u[2] = pk2(fb.x, fb.y); t.u[3] = pk2(fb.z, fb.w);
                wof[oth][kc] = t.v8;
            }
        }
        const int tt0 = tq3 * 2, tt1 = tq3 * 2 + 1;
        f32x4 aA0 = {0.f, 0.f, 0.f, 0.f}, aA1 = {0.f, 0.f, 0.f, 0.f};
        f32x4 aB0 = {0.f, 0.f, 0.f, 0.f}, aB1 = {0.f, 0.f, 0.f, 0.f};
        #pragma unroll
        for (int kc = 0; kc < 2; ++kc) {
            const int off = ((kc * 8 + qd * 2) ^ (l15 & 14)) << 2;
            bf16x8 b0 = *(const bf16x8*)(ot + (tt0 * 16 + l15) * 64 + off);
            bf16x8 b1 = *(const bf16x8*)(ot + (tt1 * 16 + l15) * 64 + off);
            aA0 = __builtin_amdgcn_mfma_f32_16x16x32_bf16(wof[0][kc], b0, aA0, 0, 0, 0);
            aA1 = __builtin_amdgcn_mfma_f32_16x16x32_bf16(wof[1][kc], b0, aA1, 0, 0, 0);
            aB0 = __builtin_amdgcn_mfma_f32_16x16x32_bf16(wof[0][kc], b1, aB0, 0, 0, 0);
            aB1 = __builtin_amdgcn_mfma_f32_16x16x32_bf16(wof[1][kc], b1, aB1, 0, 0, 0);
        }
        #pragma unroll
        for (int oth = 0; oth < 2; ++oth) {
            const int obase = (ohB + oth) * 16 + qd * 4;
            float4 bias = *(const float4*)(bo + obase);
            float bb4[4] = {bias.x, bias.y, bias.z, bias.w};
            const f32x4& c0 = oth ? aA1 : aA0;  // t-tile tt0
            const f32x4& c1 = oth ? aB1 : aB0;  // t-tile tt1
            #pragma unroll
            for (int rr = 0; rr < 4; ++rr) {
                float v0 = c0[rr] + bb4[rr]; v0 = v0 > 0.f ? v0 : 0.f;
                float v1 = c1[rr] + bb4[rr]; v1 = v1 > 0.f ? v1 : 0.f;
                float* po = out + ((b * COUT + obase + rr) * Vv + v) * Tt
                            + tq3 * 32 + l15;
                po[0]  = v0;   // both 64B halves of the 128B line,
                po[16] = v1;   // adjacent instructions, same wave
            }
        }
    }
}

extern "C" void kernel_launch(void* const* d_in, const int* in_sizes, int n_in,
                              void* d_out, int out_size, void* d_ws, size_t ws_size,
                              hipStream_t stream) {
    (void)in_sizes; (void)n_in; (void)ws_size; (void)out_size; (void)d_ws;
    const float* x   = (const float*)d_in[0];
    const float* tem = (const float*)d_in[1];
    const float* Wq  = (const float*)d_in[2];
    const float* bq  = (const float*)d_in[3];
    const float* Wk  = (const float*)d_in[4];
    const float* bk  = (const float*)d_in[5];
    const float* Wv  = (const float*)d_in[6];
    const float* bv  = (const float*)d_in[7];
    const float* Wo  = (const float*)d_in[8];
    const float* bo  = (const float*)d_in[9];
    float* out = (float*)d_out;

    tatt_fused<<<dim3(Bb * Vv), dim3(TPB), 0, stream>>>(
        x, tem, Wq, bq, Wk, bk, Wv, bv, Wo, bo, out);
}